// Round 6
// baseline (365.324 us; speedup 1.0000x reference)
//
#include <hip/hip_runtime.h>
#include <hip/hip_bf16.h>

// ChebyshevKANLayer: y[b,o] = sum_{i,j} T_j(xhat[b,i]) * C[i,o,j]
// T0==1 folded into fp32 bias; GEMM K = 1024*8 = 8192 (degrees 1..8), bf16 MFMA.
// R12: B bypasses LDS. R9's limiter was the LDS read port (128KB/tile ~1540cyc
// vs MFMA 1243cyc). B is stored FRAGMENT-MAJOR (Bf[(o>>4)*256+kb] = 64 uint4,
// one wave-fragment = one contiguous 1KB segment) and loaded straight to
// registers, prefetched one K-tile ahead. LDS carries only A (64KB/tile).
// Natural grid (8,32): id%8 = col-block -> each XCD's 2MB B slice is
// L2-resident. A path identical to R9 (DMA staging, XOR swizzle, counted
// vmcnt, 1 barrier/tile); 4 LDS buffers + x4-unrolled loop for static idx.
//   BM=256 x BN=128, BK=64, 512 thr (8 waves 4Mx2N), 4 x 32KB LDS.
// ws: bias 4KB(pad 64K) | Bf 16.8MB | A 134MB.

typedef __attribute__((ext_vector_type(8))) short bf16x8s;   // MFMA A/B frag (4 VGPRs)
typedef __attribute__((ext_vector_type(4))) float f32x4;     // MFMA C/D frag

constexpr int BROWS = 8192;
constexpr int IDIM  = 1024;
constexpr int ODIM  = 1024;
constexpr int DEG1  = 9;
constexpr int KP    = 8;             // stored degrees 1..8 per input i
constexpr int KD    = IDIM * KP;     // 8192
constexpr int NKB   = KD / 32;       // 256 k-blocks of 32

__device__ __forceinline__ ushort f2bf(float f) {
  return ((__hip_bfloat16_raw)__float2bfloat16(f)).x;
}

// async global->LDS, 16 B per lane. LDS dst MUST be wave-uniform base + lane*16.
__device__ __forceinline__ void gload_lds16(const void* g, void* l) {
  __builtin_amdgcn_global_load_lds(
      (const __attribute__((address_space(1))) unsigned int*)g,
      (__attribute__((address_space(3))) unsigned int*)l, 16, 0, 0);
}

// ---------- 1. fused rowstats + A-build (+ bias zeroing in blocks 0..3) -------
__global__ __launch_bounds__(256) void build_a_kernel(const float* __restrict__ x,
                                                      ushort* __restrict__ A2,
                                                      float* __restrict__ bias) {
  __shared__ float red[8];
  const int b = blockIdx.x, t = threadIdx.x, lane = t & 63, wv = t >> 6;
  if (b < 4) bias[b * 256 + t] = 0.0f;                     // zero before build_b
  const float* xr = x + (size_t)b * IDIM;
  const float4 v = ((const float4*)xr)[t];                 // i = 4t..4t+3
  float mn = fminf(fminf(v.x, v.y), fminf(v.z, v.w));
  float mx = fmaxf(fmaxf(v.x, v.y), fmaxf(v.z, v.w));
#pragma unroll
  for (int off = 32; off >= 1; off >>= 1) {
    mn = fminf(mn, __shfl_xor(mn, off));
    mx = fmaxf(mx, __shfl_xor(mx, off));
  }
  if (lane == 0) { red[wv] = mn; red[4 + wv] = mx; }
  __syncthreads();
  mn = fminf(fminf(red[0], red[1]), fminf(red[2], red[3]));
  mx = fmaxf(fmaxf(red[4], red[5]), fmaxf(red[6], red[7]));
  const float sc = 2.0f / (mx - mn);
  const float of = -mn * sc - 1.0f;

  uint4* adst = (uint4*)(A2 + (size_t)b * KD);
#pragma unroll
  for (int c = 0; c < 4; ++c) {
    const int i = c * 256 + t;                             // lanes consecutive
    const float xn = fmaf(sc, xr[i], of);                  // L1-hot re-read
    const float T2 = 2.f * xn * xn - 1.f;
    const float T3 = 2.f * xn * T2 - xn;
    const float T4 = 2.f * xn * T3 - T2;
    const float T5 = 2.f * xn * T4 - T3;
    const float T6 = 2.f * xn * T5 - T4;
    const float T7 = 2.f * xn * T6 - T5;
    const float T8 = 2.f * xn * T7 - T6;
    uint4 w;
    w.x = (uint)f2bf(xn) | ((uint)f2bf(T2) << 16);         // d' 0,1 = T1,T2
    w.y = (uint)f2bf(T3) | ((uint)f2bf(T4) << 16);
    w.z = (uint)f2bf(T5) | ((uint)f2bf(T6) << 16);
    w.w = (uint)f2bf(T7) | ((uint)f2bf(T8) << 16);
    adst[i] = w;                                           // coalesced 16 B/lane
  }
}

// ---------- 2. Bf fragment-major: Bf[((o>>4)*256+(i>>2))*64 + (o&15)*4+(i&3)]
//              = C[i][o][d+1] packed uint4 (8 degrees); j==0 -> fp32 bias ------
__global__ __launch_bounds__(256) void build_b_kernel(const float* __restrict__ coeffs,
                                                      uint4* __restrict__ Bf,
                                                      float* __restrict__ bias) {
  __shared__ __align__(16) ushort tile[64 * 256];          // 32 KB [o_l][i_l*8+d']
  __shared__ float lb[64];
  const int i0 = blockIdx.x * 32;
  const int o0 = blockIdx.y * 64;
  const int t  = threadIdx.x;
  if (t < 64) lb[t] = 0.0f;
  __syncthreads();
  for (int idx = t; idx < 18432; idx += 256) {             // coalesced float reads
    const int i_l = idx / 576;                             // 576 = 64*9
    const int rem = idx - i_l * 576;                       // = o_l*9 + j
    const float v = coeffs[((size_t)(i0 + i_l) * ODIM + o0) * DEG1 + rem];
    const int o_l = rem / 9;
    const int j   = rem - o_l * 9;
    if (j == 0) atomicAdd(&lb[o_l], v);                    // exact fp32 bias path
    else tile[o_l * 256 + i_l * KP + (j - 1)] = f2bf(v);
  }
  __syncthreads();
  for (int idx = t; idx < 2048; idx += 256) {              // 64B-segment writes
    const int o_l = idx >> 5;
    const int i_l = idx & 31;
    const int o = o0 + o_l, i = i0 + i_l;
    const size_t dst = ((size_t)(o >> 4) * NKB + (i >> 2)) * 64 + (o & 15) * 4 + (i & 3);
    Bf[dst] = ((const uint4*)tile)[idx];
  }
  if (t < 64) atomicAdd(&bias[o0 + t], lb[t]);             // device-scope fp32 add
}

// ---------- 3. GEMM: 256x128, BK=64, A via LDS (4 bufs), B reg-direct ---------
// Per K-tile: [prefetch B(it+1) 8x global uint4 | issue 4x A-DMA for it+2]
// then 2 phases {4 ds_read_b128 ; 16 MFMA (setprio)}; end: vmcnt(12) (12 =
// B(it+1)8 + ADMA(it+2)4 issued after ADMA(it+1)) + ONE barrier. B frag =
// contiguous 1KB at Bf[(c0>>4)*NKB + kb] + lane-permuted 16B -> coalesced,
// L2-resident (grid id%8 = col-block -> XCD owns 2MB B slice).
__global__ __launch_bounds__(512, 2) void gemm_kernel(const ushort* __restrict__ A2,
                                                      const uint4* __restrict__ Bf,
                                                      const float* __restrict__ bias,
                                                      float* __restrict__ out) {
  constexpr int BK   = 64;
  constexpr int KT   = KD / BK;        // 128 K-tiles
  constexpr int ABUF = 256 * BK;       // 16384 ushorts = 32 KB
  __shared__ __align__(16) ushort Sm[4 * ABUF];    // 128 KB -> 1 block/CU

  const int t    = threadIdx.x;
  const int lane = t & 63;
  const int wave = t >> 6;
  const int wr   = wave >> 1;          // 0..3 : M sub-block (64 rows each)
  const int wc   = wave & 1;           // 0..1 : N sub-block (64 cols each)
  const int c16  = lane & 15;
  const int quad = lane >> 4;

  const int rowBase = blockIdx.y * 256;            // grid (8,32): id%8 = col-block
  const int colBase = blockIdx.x * 128;            // -> XCD k owns col slice k

  // A staging: thread t covers row t>>3 (+64/sweep), 16B chunk (t&7)^(row&7)
  const int trow = t >> 3;                         // 0..63
  const int scol = (t & 7) ^ (trow & 7);
  const ushort* aB = A2 + (size_t)(rowBase + trow) * KD + scol * 8;
  ushort* uA = Sm + t * 8;                         // wave-uniform base + lane*16B

  auto issA = [&](int buf, int itile, int a) {
    gload_lds16(aB + (size_t)a * (64 * KD) + (size_t)itile * BK,
                uA + buf * ABUF + a * 4096);
  };

  // B fragment bases: n-tile col c0 = colBase + wc*64 + n*16
  const int bq = c16 * 4 + quad;                   // in-segment permutation
  const uint4* Bn[4];
#pragma unroll
  for (int n = 0; n < 4; ++n)
    Bn[n] = Bf + ((size_t)(colBase / 16 + wc * 4 + n) * NKB) * 64 + bq;
  // frag for (n, kb): Bn[n][kb*64]; kb = it*2 + kh

  // per-wave LDS A read offsets; swizzled 16B chunk per kh
  const int aoff = (wr * 64 + c16) * BK;
  const int cx0  = ((0 + quad) ^ (c16 & 7)) * 8;
  const int cx1  = ((4 + quad) ^ (c16 & 7)) * 8;

  f32x4 acc[4][4];
#pragma unroll
  for (int m = 0; m < 4; ++m)
#pragma unroll
    for (int n = 0; n < 4; ++n) acc[m][n] = (f32x4){0.f, 0.f, 0.f, 0.f};

  bf16x8s bfr[2][8];                               // [tile parity][kh*4+n]

  // prologue: B(0) -> bfr[0]; ADMA tiles 0,1 -> bufs 0,1; B(1) -> bfr[1]
#pragma unroll
  for (int n = 0; n < 4; ++n) {
    bfr[0][n]     = *(const bf16x8s*)&Bn[n][0];
    bfr[0][4 + n] = *(const bf16x8s*)&Bn[n][64];
  }
  issA(0, 0, 0); issA(0, 0, 1); issA(0, 0, 2); issA(0, 0, 3);
  issA(1, 1, 0); issA(1, 1, 1); issA(1, 1, 2); issA(1, 1, 3);
#pragma unroll
  for (int n = 0; n < 4; ++n) {
    bfr[1][n]     = *(const bf16x8s*)&Bn[n][2 * 64];
    bfr[1][4 + n] = *(const bf16x8s*)&Bn[n][3 * 64];
  }
  asm volatile("s_waitcnt vmcnt(12)" ::: "memory");  // ADMA(0)+B(0) complete
  __builtin_amdgcn_s_barrier();

  for (int itb = 0; itb < KT; itb += 4) {
#pragma unroll
    for (int J = 0; J < 4; ++J) {                  // buffer for tile it is it&3==J
      const int it = itb + J;
      const ushort* Asb = Sm + J * ABUF;

      if (it + 1 < KT) {                           // B prefetch -> bfr[(J+1)&1]
        const size_t kb0 = (size_t)(it + 1) * 2 * 64;
#pragma unroll
        for (int n = 0; n < 4; ++n) {
          bfr[(J + 1) & 1][n]     = *(const bf16x8s*)&Bn[n][kb0];
          bfr[(J + 1) & 1][4 + n] = *(const bf16x8s*)&Bn[n][kb0 + 64];
        }
      }
      if (it + 2 < KT) {                           // A DMA -> buf (J+2)&3
        issA((J + 2) & 3, it + 2, 0); issA((J + 2) & 3, it + 2, 1);
        issA((J + 2) & 3, it + 2, 2); issA((J + 2) & 3, it + 2, 3);
      }

      {                                            // ---- phase 0 (k 0..31) ----
        bf16x8s afr[4];
#pragma unroll
        for (int m = 0; m < 4; ++m)
          afr[m] = *(const bf16x8s*)&Asb[aoff + m * (16 * BK) + cx0];
        __builtin_amdgcn_s_setprio(1);
#pragma unroll
        for (int m = 0; m < 4; ++m)
#pragma unroll
          for (int n = 0; n < 4; ++n)
            acc[m][n] = __builtin_amdgcn_mfma_f32_16x16x32_bf16(
                afr[m], bfr[J & 1][n], acc[m][n], 0, 0, 0);
        __builtin_amdgcn_s_setprio(0);
      }
      {                                            // ---- phase 1 (k 32..63) ----
        bf16x8s afr[4];
#pragma unroll
        for (int m = 0; m < 4; ++m)
          afr[m] = *(const bf16x8s*)&Asb[aoff + m * (16 * BK) + cx1];
        __builtin_amdgcn_s_setprio(1);
#pragma unroll
        for (int m = 0; m < 4; ++m)
#pragma unroll
          for (int n = 0; n < 4; ++n)
            acc[m][n] = __builtin_amdgcn_mfma_f32_16x16x32_bf16(
                afr[m], bfr[J & 1][4 + n], acc[m][n], 0, 0, 0);
        __builtin_amdgcn_s_setprio(0);
      }

      if (it < KT - 2) { asm volatile("s_waitcnt vmcnt(12)" ::: "memory"); }
      else             { asm volatile("s_waitcnt vmcnt(0)"  ::: "memory"); }
      __builtin_amdgcn_s_barrier();                // ONE barrier per K-tile
    }
  }

  // ---- epilogue: straight from registers, add bias ----
#pragma unroll
  for (int n = 0; n < 4; ++n) {
    const int col = colBase + wc * 64 + n * 16 + c16;
    const float bv = bias[col];
#pragma unroll
    for (int m = 0; m < 4; ++m) {
      const int r0 = rowBase + wr * 64 + m * 16 + quad * 4;
#pragma unroll
      for (int r = 0; r < 4; ++r)
        out[(size_t)(r0 + r) * ODIM + col] = acc[m][n][r] + bv;
    }
  }
}

extern "C" void kernel_launch(void* const* d_in, const int* in_sizes, int n_in,
                              void* d_out, int out_size, void* d_ws, size_t ws_size,
                              hipStream_t stream) {
  const float* x      = (const float*)d_in[0];   // [8192,1024] fp32
  const float* coeffs = (const float*)d_in[1];   // [1024,1024,9] fp32
  float* out = (float*)d_out;                    // [8192,1024] fp32

  char* ws = (char*)d_ws;
  float* bias = (float*)ws;                                         // 4 KB (pad 64K)
  uint4* Bf   = (uint4*)(ws + 65536);                               // 16.78 MB
  ushort* A2  = (ushort*)(ws + 65536 + (size_t)ODIM * KD * 2);      // 134.2 MB
  // total ws: ~151 MB

  build_a_kernel<<<BROWS, 256, 0, stream>>>(x, A2, bias);           // zeroes bias too
  build_b_kernel<<<dim3(IDIM / 32, ODIM / 64), 256, 0, stream>>>(coeffs, Bf, bias);
  // 256x128 tile -> grid (ODIM/128, BROWS/256) = (8, 32); id%8 = col-block = XCD
  gemm_kernel<<<dim3(ODIM / 128, BROWS / 256), 512, 0, stream>>>(A2, Bf, bias, out);
}

// Round 7
// 297.529 us; speedup vs baseline: 1.2279x; 1.2279x over previous
//
#include <hip/hip_runtime.h>
#include <hip/hip_bf16.h>

// ChebyshevKANLayer: y[b,o] = sum_{i,j} T_j(xhat[b,i]) * C[i,o,j]
// T0==1 folded into fp32 bias; GEMM K = 1024*8 = 8192 (degrees 1..8), bf16 MFMA.
// R13: fat waves. R12 (reg-B) regressed: 4x B duplication + lost XCD swizzle.
// R9's true limiter is LDS bytes/FLOP of the 64x64 wave tile (0.031 B/F >
// port balance 0.025). This round: BM=256 x BN=128, 256 thr = 4 waves of
// 128x64 (0.0234 B/F -> compute-bound), BK=32, 3 x 24KB LDS buffers ->
// 2 blocks/CU (8 waves/CU, inter-block overlap covers barrier stalls).
// Keep everything proven: counted vmcnt(6), 1 barrier/tile, setprio, R9 XCD
// chunk swizzle, R11's conflict-free 4-chunk XOR (measured 0 conflicts),
// bias zeroing folded into build_a.
// ws: bias 4KB(pad 64K) | B^T 16.8MB | A 134MB.

typedef __attribute__((ext_vector_type(8))) short bf16x8s;   // MFMA A/B frag (4 VGPRs)
typedef __attribute__((ext_vector_type(4))) float f32x4;     // MFMA C/D frag

constexpr int BROWS = 8192;
constexpr int IDIM  = 1024;
constexpr int ODIM  = 1024;
constexpr int DEG1  = 9;
constexpr int KP    = 8;             // stored degrees 1..8 per input i
constexpr int KD    = IDIM * KP;     // 8192

__device__ __forceinline__ ushort f2bf(float f) {
  return ((__hip_bfloat16_raw)__float2bfloat16(f)).x;
}

// async global->LDS, 16 B per lane. LDS dst MUST be wave-uniform base + lane*16.
__device__ __forceinline__ void gload_lds16(const void* g, void* l) {
  __builtin_amdgcn_global_load_lds(
      (const __attribute__((address_space(1))) unsigned int*)g,
      (__attribute__((address_space(3))) unsigned int*)l, 16, 0, 0);
}

// ---------- 1. fused rowstats + A-build (+ bias zeroing in blocks 0..3) -------
__global__ __launch_bounds__(256) void build_a_kernel(const float* __restrict__ x,
                                                      ushort* __restrict__ A2,
                                                      float* __restrict__ bias) {
  __shared__ float red[8];
  const int b = blockIdx.x, t = threadIdx.x, lane = t & 63, wv = t >> 6;
  if (b < 4) bias[b * 256 + t] = 0.0f;                     // zero before build_b
  const float* xr = x + (size_t)b * IDIM;
  const float4 v = ((const float4*)xr)[t];                 // i = 4t..4t+3
  float mn = fminf(fminf(v.x, v.y), fminf(v.z, v.w));
  float mx = fmaxf(fmaxf(v.x, v.y), fmaxf(v.z, v.w));
#pragma unroll
  for (int off = 32; off >= 1; off >>= 1) {
    mn = fminf(mn, __shfl_xor(mn, off));
    mx = fmaxf(mx, __shfl_xor(mx, off));
  }
  if (lane == 0) { red[wv] = mn; red[4 + wv] = mx; }
  __syncthreads();
  mn = fminf(fminf(red[0], red[1]), fminf(red[2], red[3]));
  mx = fmaxf(fmaxf(red[4], red[5]), fmaxf(red[6], red[7]));
  const float sc = 2.0f / (mx - mn);
  const float of = -mn * sc - 1.0f;

  uint4* adst = (uint4*)(A2 + (size_t)b * KD);
#pragma unroll
  for (int c = 0; c < 4; ++c) {
    const int i = c * 256 + t;                             // lanes consecutive
    const float xn = fmaf(sc, xr[i], of);                  // L1-hot re-read
    const float T2 = 2.f * xn * xn - 1.f;
    const float T3 = 2.f * xn * T2 - xn;
    const float T4 = 2.f * xn * T3 - T2;
    const float T5 = 2.f * xn * T4 - T3;
    const float T6 = 2.f * xn * T5 - T4;
    const float T7 = 2.f * xn * T6 - T5;
    const float T8 = 2.f * xn * T7 - T6;
    uint4 w;
    w.x = (uint)f2bf(xn) | ((uint)f2bf(T2) << 16);         // d' 0,1 = T1,T2
    w.y = (uint)f2bf(T3) | ((uint)f2bf(T4) << 16);
    w.z = (uint)f2bf(T5) | ((uint)f2bf(T6) << 16);
    w.w = (uint)f2bf(T7) | ((uint)f2bf(T8) << 16);
    adst[i] = w;                                           // coalesced 16 B/lane
  }
}

// ---------- 2. B^T[o][i*8+d'] = C[i][o][d'+1] bf16; j==0 -> fp32 bias ----------
__global__ __launch_bounds__(256) void build_b_kernel(const float* __restrict__ coeffs,
                                                      ushort* __restrict__ B2T,
                                                      float* __restrict__ bias) {
  __shared__ __align__(16) ushort tile[64 * 256];          // 32 KB [o_l][i_l*8+d']
  __shared__ float lb[64];
  const int i0 = blockIdx.x * 32;
  const int o0 = blockIdx.y * 64;
  const int t  = threadIdx.x;
  if (t < 64) lb[t] = 0.0f;
  __syncthreads();
  for (int idx = t; idx < 18432; idx += 256) {             // coalesced float reads
    const int i_l = idx / 576;                             // 576 = 64*9
    const int rem = idx - i_l * 576;                       // = o_l*9 + j
    const float v = coeffs[((size_t)(i0 + i_l) * ODIM + o0) * DEG1 + rem];
    const int o_l = rem / 9;
    const int j   = rem - o_l * 9;
    if (j == 0) atomicAdd(&lb[o_l], v);                    // exact fp32 bias path
    else tile[o_l * 256 + i_l * KP + (j - 1)] = f2bf(v);
  }
  __syncthreads();
  for (int idx = t; idx < 2048; idx += 256) {              // coalesced uint4 writes
    const int o_l = idx >> 5;
    const int w   = idx & 31;
    uint4* gdst = (uint4*)(B2T + (size_t)(o0 + o_l) * KD + i0 * KP);
    gdst[w] = ((const uint4*)tile)[idx];
  }
  if (t < 64) atomicAdd(&bias[o0 + t], lb[t]);             // device-scope fp32 add
}

// ---------- 3. GEMM: 256x128, 4 waves of 128x64, BK=32, 2 blocks/CU -----------
// Per K-tile: {12 ds_read_b128 | issue 6 gload_lds | 32 MFMA (setprio)} ;
// vmcnt(6) ; s_barrier. Triple buffer (tile it -> buf it%3): reads hit cur,
// staging hits nb = (cur+2)%3 (tile it-1's buffer, consumed before the
// previous barrier). Steady state 12 loads in flight; vmcnt(6) completes
// tile it+1's, leaves it+2's 6 in flight across the barrier.
__global__ __launch_bounds__(256, 2) void gemm_kernel(const ushort* __restrict__ A2,
                                                      const ushort* __restrict__ B2T,
                                                      const float* __restrict__ bias,
                                                      float* __restrict__ out) {
  constexpr int BK    = 32;
  constexpr int KT    = KD / BK;       // 256 K-tiles
  constexpr int ABUFU = 256 * BK;      // 8192 ushorts = 16 KB
  constexpr int BBUFU = 128 * BK;      // 4096 ushorts =  8 KB
  constexpr int BUFSZ = ABUFU + BBUFU; // 12288 ushorts = 24 KB
  __shared__ __align__(16) ushort Sm[3 * BUFSZ];   // 72 KB -> 2 blocks/CU

  const int t    = threadIdx.x;
  const int lane = t & 63;
  const int wave = t >> 6;
  const int wr   = wave >> 1;          // 0..1 : 128-row half
  const int wc   = wave & 1;           // 0..1 : 64-col half
  const int c16  = lane & 15;
  const int quad = lane >> 4;

  // bijective XCD chunk swizzle (256 wgs % 8 == 0): XCD k -> rows 4k..4k+3, all cols
  const int orig = blockIdx.y * 8 + blockIdx.x;    // grid (8, 32), x = col fastest
  const int swz  = (orig & 7) * 32 + (orig >> 3);
  const int rowBase = (swz >> 3) * 256;
  const int colBase = (swz & 7) * 128;

  // staging: thread t covers row t>>2 (+64/sweep), 16B chunk t&3; global chunk
  // XOR-permuted with f(row)=(row>>1)&3 (R11 scheme, measured 0 conflicts).
  const int trow = t >> 2;                         // 0..63
  const int scol = (t & 3) ^ ((t >> 3) & 3);       // (t&3) ^ f(trow)
  const ushort* aB = A2  + (size_t)(rowBase + trow) * KD + scol * 8;
  const ushort* bB = B2T + (size_t)(colBase + trow) * KD + scol * 8;
  ushort* uA = Sm + t * 8;                         // wave-uniform base + lane*16B
  ushort* uB = Sm + ABUFU + t * 8;

  auto issA = [&](int buf, int itile, int a) {     // a = 0..3 : 64-row sweeps
    gload_lds16(aB + (size_t)a * (64 * KD) + (size_t)itile * BK,
                uA + buf * BUFSZ + a * 2048);
  };
  auto issB = [&](int buf, int itile, int b2) {    // b2 = 0..1 : 64-row sweeps
    gload_lds16(bB + (size_t)b2 * (64 * KD) + (size_t)itile * BK,
                uB + buf * BUFSZ + b2 * 2048);
  };

  // per-wave LDS read offsets (ushort idx); swizzled 16B chunk = quad ^ f(c16)
  const int cx   = (quad ^ ((c16 >> 1) & 3)) * 8;
  const int aoff = (wr * 128 + c16) * BK + cx;     // + m*16*BK per m-tile
  const int boff = (wc * 64 + c16) * BK + cx;      // + n*16*BK per n-tile

  f32x4 acc[8][4];
#pragma unroll
  for (int m = 0; m < 8; ++m)
#pragma unroll
    for (int n = 0; n < 4; ++n) acc[m][n] = (f32x4){0.f, 0.f, 0.f, 0.f};

  // prologue: stage tiles 0,1 -> bufs 0,1 ; complete tile 0 (6 left in flight)
  issA(0, 0, 0); issA(0, 0, 1); issA(0, 0, 2); issA(0, 0, 3);
  issB(0, 0, 0); issB(0, 0, 1);
  issA(1, 1, 0); issA(1, 1, 1); issA(1, 1, 2); issA(1, 1, 3);
  issB(1, 1, 0); issB(1, 1, 1);
  asm volatile("s_waitcnt vmcnt(6)" ::: "memory");
  __builtin_amdgcn_s_barrier();

  int cur = 0;
  for (int it = 0; it < KT; ++it) {
    const ushort* Asb = Sm + cur * BUFSZ;
    const ushort* Bsb = Asb + ABUFU;
    const int nb = (cur >= 1) ? cur - 1 : 2;       // (cur+2)%3: held tile it-1
    const bool pf = (it < KT - 2);

    bf16x8s afr[8], bfr[4];
#pragma unroll
    for (int m = 0; m < 8; ++m)
      afr[m] = *(const bf16x8s*)&Asb[aoff + m * (16 * BK)];
#pragma unroll
    for (int n = 0; n < 4; ++n)
      bfr[n] = *(const bf16x8s*)&Bsb[boff + n * (16 * BK)];

    if (pf) {
      issA(nb, it + 2, 0); issA(nb, it + 2, 1);
      issA(nb, it + 2, 2); issA(nb, it + 2, 3);
      issB(nb, it + 2, 0); issB(nb, it + 2, 1);
    }

    __builtin_amdgcn_s_setprio(1);
#pragma unroll
    for (int m = 0; m < 8; ++m)
#pragma unroll
      for (int n = 0; n < 4; ++n)
        acc[m][n] = __builtin_amdgcn_mfma_f32_16x16x32_bf16(afr[m], bfr[n],
                                                            acc[m][n], 0, 0, 0);
    __builtin_amdgcn_s_setprio(0);

    if (pf)              { asm volatile("s_waitcnt vmcnt(6)" ::: "memory"); }
    else if (it == KT-2) { asm volatile("s_waitcnt vmcnt(0)" ::: "memory"); }
    __builtin_amdgcn_s_barrier();                  // ONE barrier per K-tile

    cur = (cur == 2) ? 0 : cur + 1;
  }

  // ---- epilogue: straight from registers, add bias ----
#pragma unroll
  for (int n = 0; n < 4; ++n) {
    const int col = colBase + wc * 64 + n * 16 + c16;
    const float bv = bias[col];
#pragma unroll
    for (int m = 0; m < 8; ++m) {
      const int r0 = rowBase + wr * 128 + m * 16 + quad * 4;
#pragma unroll
      for (int r = 0; r < 4; ++r)
        out[(size_t)(r0 + r) * ODIM + col] = acc[m][n][r] + bv;
    }
  }
}

extern "C" void kernel_launch(void* const* d_in, const int* in_sizes, int n_in,
                              void* d_out, int out_size, void* d_ws, size_t ws_size,
                              hipStream_t stream) {
  const float* x      = (const float*)d_in[0];   // [8192,1024] fp32
  const float* coeffs = (const float*)d_in[1];   // [1024,1024,9] fp32
  float* out = (float*)d_out;                    // [8192,1024] fp32

  char* ws = (char*)d_ws;
  float*  bias = (float*)ws;                                        // 4 KB (pad 64K)
  ushort* B2T  = (ushort*)(ws + 65536);                             // 16.78 MB
  ushort* A2   = (ushort*)(ws + 65536 + (size_t)ODIM * KD * 2);     // 134.2 MB
  // total ws: ~151 MB

  build_a_kernel<<<BROWS, 256, 0, stream>>>(x, A2, bias);           // zeroes bias too
  build_b_kernel<<<dim3(IDIM / 32, ODIM / 64), 256, 0, stream>>>(coeffs, B2T, bias);
  // 256x128 tile -> grid (ODIM/128, BROWS/256) = (8, 32) = 256 blocks = 1/CU-pair
  gemm_kernel<<<dim3(ODIM / 128, BROWS / 256), 256, 0, stream>>>(A2, B2T, bias, out);
}

// Round 8
// 293.472 us; speedup vs baseline: 1.2448x; 1.0138x over previous
//
#include <hip/hip_runtime.h>
#include <hip/hip_bf16.h>

// ChebyshevKANLayer: y[b,o] = sum_{i,j} T_j(xhat[b,i]) * C[i,o,j]
// T0==1 folded into fp32 bias; GEMM K = 1024*8 = 8192 (degrees 1..8), bf16 MFMA.
// R14: fat waves + in-block split-K. R13 failed on occupancy (grid fixed at 256
// blocks -> 256-thr block = 4 waves/CU = starved SIMDs). Fat 128x64 waves can
// only reach 8 waves/CU by splitting K: 512 thr = 2 k-groups x 4 waves(128x64),
// group g owns k in [g*4096, g*4096+4096) as 128 tiles of BK=32, own 3x24KB
// LDS region (144 KB total). Per-iter/CU: LDS 96KB (~1129cyc) < MFMA 1242cyc
// -> matrix pipe finally binding. Epilogue: R6's verified split-K combine
// (group1 parks acc in LDS fp32, group0 adds + bias). Keep: counted vmcnt(6),
// 1 barrier/tile, setprio, XCD chunk swizzle, conflict-free 4-chunk XOR.
// ws: bias 4KB(pad 64K) | B^T 16.8MB | A 134MB.

typedef __attribute__((ext_vector_type(8))) short bf16x8s;   // MFMA A/B frag (4 VGPRs)
typedef __attribute__((ext_vector_type(4))) float f32x4;     // MFMA C/D frag

constexpr int BROWS = 8192;
constexpr int IDIM  = 1024;
constexpr int ODIM  = 1024;
constexpr int DEG1  = 9;
constexpr int KP    = 8;             // stored degrees 1..8 per input i
constexpr int KD    = IDIM * KP;     // 8192
constexpr int KH    = KD / 2;        // 4096 per k-group

__device__ __forceinline__ ushort f2bf(float f) {
  return ((__hip_bfloat16_raw)__float2bfloat16(f)).x;
}

// async global->LDS, 16 B per lane. LDS dst MUST be wave-uniform base + lane*16.
__device__ __forceinline__ void gload_lds16(const void* g, void* l) {
  __builtin_amdgcn_global_load_lds(
      (const __attribute__((address_space(1))) unsigned int*)g,
      (__attribute__((address_space(3))) unsigned int*)l, 16, 0, 0);
}

// ---------- 1. fused rowstats + A-build (+ bias zeroing in blocks 0..3) -------
__global__ __launch_bounds__(256) void build_a_kernel(const float* __restrict__ x,
                                                      ushort* __restrict__ A2,
                                                      float* __restrict__ bias) {
  __shared__ float red[8];
  const int b = blockIdx.x, t = threadIdx.x, lane = t & 63, wv = t >> 6;
  if (b < 4) bias[b * 256 + t] = 0.0f;                     // zero before build_b
  const float* xr = x + (size_t)b * IDIM;
  const float4 v = ((const float4*)xr)[t];                 // i = 4t..4t+3
  float mn = fminf(fminf(v.x, v.y), fminf(v.z, v.w));
  float mx = fmaxf(fmaxf(v.x, v.y), fmaxf(v.z, v.w));
#pragma unroll
  for (int off = 32; off >= 1; off >>= 1) {
    mn = fminf(mn, __shfl_xor(mn, off));
    mx = fmaxf(mx, __shfl_xor(mx, off));
  }
  if (lane == 0) { red[wv] = mn; red[4 + wv] = mx; }
  __syncthreads();
  mn = fminf(fminf(red[0], red[1]), fminf(red[2], red[3]));
  mx = fmaxf(fmaxf(red[4], red[5]), fmaxf(red[6], red[7]));
  const float sc = 2.0f / (mx - mn);
  const float of = -mn * sc - 1.0f;

  uint4* adst = (uint4*)(A2 + (size_t)b * KD);
#pragma unroll
  for (int c = 0; c < 4; ++c) {
    const int i = c * 256 + t;                             // lanes consecutive
    const float xn = fmaf(sc, xr[i], of);                  // L1-hot re-read
    const float T2 = 2.f * xn * xn - 1.f;
    const float T3 = 2.f * xn * T2 - xn;
    const float T4 = 2.f * xn * T3 - T2;
    const float T5 = 2.f * xn * T4 - T3;
    const float T6 = 2.f * xn * T5 - T4;
    const float T7 = 2.f * xn * T6 - T5;
    const float T8 = 2.f * xn * T7 - T6;
    uint4 w;
    w.x = (uint)f2bf(xn) | ((uint)f2bf(T2) << 16);         // d' 0,1 = T1,T2
    w.y = (uint)f2bf(T3) | ((uint)f2bf(T4) << 16);
    w.z = (uint)f2bf(T5) | ((uint)f2bf(T6) << 16);
    w.w = (uint)f2bf(T7) | ((uint)f2bf(T8) << 16);
    adst[i] = w;                                           // coalesced 16 B/lane
  }
}

// ---------- 2. B^T[o][i*8+d'] = C[i][o][d'+1] bf16; j==0 -> fp32 bias ----------
__global__ __launch_bounds__(256) void build_b_kernel(const float* __restrict__ coeffs,
                                                      ushort* __restrict__ B2T,
                                                      float* __restrict__ bias) {
  __shared__ __align__(16) ushort tile[64 * 256];          // 32 KB [o_l][i_l*8+d']
  __shared__ float lb[64];
  const int i0 = blockIdx.x * 32;
  const int o0 = blockIdx.y * 64;
  const int t  = threadIdx.x;
  if (t < 64) lb[t] = 0.0f;
  __syncthreads();
  for (int idx = t; idx < 18432; idx += 256) {             // coalesced float reads
    const int i_l = idx / 576;                             // 576 = 64*9
    const int rem = idx - i_l * 576;                       // = o_l*9 + j
    const float v = coeffs[((size_t)(i0 + i_l) * ODIM + o0) * DEG1 + rem];
    const int o_l = rem / 9;
    const int j   = rem - o_l * 9;
    if (j == 0) atomicAdd(&lb[o_l], v);                    // exact fp32 bias path
    else tile[o_l * 256 + i_l * KP + (j - 1)] = f2bf(v);
  }
  __syncthreads();
  for (int idx = t; idx < 2048; idx += 256) {              // coalesced uint4 writes
    const int o_l = idx >> 5;
    const int w   = idx & 31;
    uint4* gdst = (uint4*)(B2T + (size_t)(o0 + o_l) * KD + i0 * KP);
    gdst[w] = ((const uint4*)tile)[idx];
  }
  if (t < 64) atomicAdd(&bias[o0 + t], lb[t]);             // device-scope fp32 add
}

// ---------- 3. GEMM: 256x128, 2 k-groups x 4 waves(128x64), BK=32 -------------
// Per K-tile per group: {12 ds_read_b128 | issue 6 gload_lds | 32 MFMA} ;
// vmcnt(6) ; s_barrier (block-wide, groups symmetric). Triple buffer per
// group: reads hit cur; staging hits nb = tile it-1's buffer (consumed
// before the previous barrier). Epilogue: group1 parks acc in LDS fp32
// (Sm reused, 128KB), group0 adds + bias + stores.
__global__ __launch_bounds__(512, 1) void gemm_kernel(const ushort* __restrict__ A2,
                                                      const ushort* __restrict__ B2T,
                                                      const float* __restrict__ bias,
                                                      float* __restrict__ out) {
  constexpr int BK    = 32;
  constexpr int KT    = KH / BK;       // 128 K-tiles per group
  constexpr int ABUFU = 256 * BK;      // 8192 ushorts = 16 KB
  constexpr int BBUFU = 128 * BK;      // 4096 ushorts =  8 KB
  constexpr int BUFSZ = ABUFU + BBUFU; // 12288 ushorts = 24 KB
  __shared__ __align__(16) ushort Sm[2 * 3 * BUFSZ];   // 144 KB -> 1 block/CU

  const int t    = threadIdx.x;
  const int lane = t & 63;
  const int wave = t >> 6;
  const int g    = wave >> 2;          // k-group 0/1
  const int w4   = wave & 3;
  const int wr   = w4 >> 1;            // 0..1 : 128-row half
  const int wc   = w4 & 1;             // 0..1 : 64-col half
  const int c16  = lane & 15;
  const int quad = lane >> 4;

  // bijective XCD chunk swizzle (256 wgs % 8 == 0): XCD k -> rows 4k..4k+3, all cols
  const int orig = blockIdx.y * 8 + blockIdx.x;    // grid (8, 32), x = col fastest
  const int swz  = (orig & 7) * 32 + (orig >> 3);
  const int rowBase = (swz >> 3) * 256;
  const int colBase = (swz & 7) * 128;

  // staging (per group, 256 threads): thread tp covers row tp>>2 (+64/sweep),
  // 16B chunk (tp&3)^f(row), f(row)=(row>>1)&3 (R11/R13 scheme, 0 conflicts).
  const int tp   = t & 255;
  const int trow = tp >> 2;                        // 0..63
  const int scol = (tp & 3) ^ ((tp >> 3) & 3);     // (tp&3) ^ f(trow)
  const ushort* aB = A2  + (size_t)(rowBase + trow) * KD + (size_t)g * KH + scol * 8;
  const ushort* bB = B2T + (size_t)(colBase + trow) * KD + (size_t)g * KH + scol * 8;
  ushort* SmG = Sm + g * (3 * BUFSZ);              // group LDS region
  ushort* uA  = SmG + tp * 8;                      // wave-uniform base + lane*16B
  ushort* uB  = SmG + ABUFU + tp * 8;

  auto issA = [&](int buf, int itile, int a) {     // a = 0..3 : 64-row sweeps
    gload_lds16(aB + (size_t)a * (64 * KD) + (size_t)itile * BK,
                uA + buf * BUFSZ + a * 2048);
  };
  auto issB = [&](int buf, int itile, int b2) {    // b2 = 0..1 : 64-row sweeps
    gload_lds16(bB + (size_t)b2 * (64 * KD) + (size_t)itile * BK,
                uB + buf * BUFSZ + b2 * 2048);
  };

  // per-wave LDS read offsets (ushort idx); swizzled 16B chunk = quad ^ f(c16)
  const int cx   = (quad ^ ((c16 >> 1) & 3)) * 8;
  const int aoff = (wr * 128 + c16) * BK + cx;     // + m*16*BK per m-tile
  const int boff = (wc * 64 + c16) * BK + cx;      // + n*16*BK per n-tile

  f32x4 acc[8][4];
#pragma unroll
  for (int m = 0; m < 8; ++m)
#pragma unroll
    for (int n = 0; n < 4; ++n) acc[m][n] = (f32x4){0.f, 0.f, 0.f, 0.f};

  // prologue: stage tiles 0,1 -> bufs 0,1 ; complete tile 0 (6 left in flight)
  issA(0, 0, 0); issA(0, 0, 1); issA(0, 0, 2); issA(0, 0, 3);
  issB(0, 0, 0); issB(0, 0, 1);
  issA(1, 1, 0); issA(1, 1, 1); issA(1, 1, 2); issA(1, 1, 3);
  issB(1, 1, 0); issB(1, 1, 1);
  asm volatile("s_waitcnt vmcnt(6)" ::: "memory");
  __builtin_amdgcn_s_barrier();

  int cur = 0;
  for (int it = 0; it < KT; ++it) {
    const ushort* Asb = SmG + cur * BUFSZ;
    const ushort* Bsb = Asb + ABUFU;
    const int nb = (cur >= 1) ? cur - 1 : 2;       // (cur+2)%3: held tile it-1
    const bool pf = (it < KT - 2);

    bf16x8s afr[8], bfr[4];
#pragma unroll
    for (int m = 0; m < 8; ++m)
      afr[m] = *(const bf16x8s*)&Asb[aoff + m * (16 * BK)];
#pragma unroll
    for (int n = 0; n < 4; ++n)
      bfr[n] = *(const bf16x8s*)&Bsb[boff + n * (16 * BK)];

    if (pf) {
      issA(nb, it + 2, 0); issA(nb, it + 2, 1);
      issA(nb, it + 2, 2); issA(nb, it + 2, 3);
      issB(nb, it + 2, 0); issB(nb, it + 2, 1);
    }

    __builtin_amdgcn_s_setprio(1);
#pragma unroll
    for (int m = 0; m < 8; ++m)
#pragma unroll
      for (int n = 0; n < 4; ++n)
        acc[m][n] = __builtin_amdgcn_mfma_f32_16x16x32_bf16(afr[m], bfr[n],
                                                            acc[m][n], 0, 0, 0);
    __builtin_amdgcn_s_setprio(0);

    if (pf)              { asm volatile("s_waitcnt vmcnt(6)" ::: "memory"); }
    else if (it == KT-2) { asm volatile("s_waitcnt vmcnt(0)" ::: "memory"); }
    __builtin_amdgcn_s_barrier();                  // ONE barrier per K-tile

    cur = (cur == 2) ? 0 : cur + 1;
  }

  // ---- epilogue: combine k-groups through LDS, add bias, store ----
  __syncthreads();                                 // all frag reads done; Sm reusable
  float* Ct = (float*)Sm;                          // 256x128 fp32 = 128 KB
  if (g == 1) {
#pragma unroll
    for (int m = 0; m < 8; ++m)
#pragma unroll
      for (int n = 0; n < 4; ++n) {
        const int lr0 = wr * 128 + m * 16 + quad * 4;
        const int cl  = wc * 64 + n * 16 + c16;
#pragma unroll
        for (int r = 0; r < 4; ++r) Ct[(lr0 + r) * 128 + cl] = acc[m][n][r];
      }
  }
  __syncthreads();
  if (g == 0) {
#pragma unroll
    for (int n = 0; n < 4; ++n) {
      const int cl = wc * 64 + n * 16 + c16;
      const float bv = bias[colBase + cl];
#pragma unroll
      for (int m = 0; m < 8; ++m) {
        const int lr0 = wr * 128 + m * 16 + quad * 4;
#pragma unroll
        for (int r = 0; r < 4; ++r)
          out[(size_t)(rowBase + lr0 + r) * ODIM + colBase + cl] =
              acc[m][n][r] + Ct[(lr0 + r) * 128 + cl] + bv;
      }
    }
  }
}

extern "C" void kernel_launch(void* const* d_in, const int* in_sizes, int n_in,
                              void* d_out, int out_size, void* d_ws, size_t ws_size,
                              hipStream_t stream) {
  const float* x      = (const float*)d_in[0];   // [8192,1024] fp32
  const float* coeffs = (const float*)d_in[1];   // [1024,1024,9] fp32
  float* out = (float*)d_out;                    // [8192,1024] fp32

  char* ws = (char*)d_ws;
  float*  bias = (float*)ws;                                        // 4 KB (pad 64K)
  ushort* B2T  = (ushort*)(ws + 65536);                             // 16.78 MB
  ushort* A2   = (ushort*)(ws + 65536 + (size_t)ODIM * KD * 2);     // 134.2 MB
  // total ws: ~151 MB

  build_a_kernel<<<BROWS, 256, 0, stream>>>(x, A2, bias);           // zeroes bias too
  build_b_kernel<<<dim3(IDIM / 32, ODIM / 64), 256, 0, stream>>>(coeffs, B2T, bias);
  // 256x128 tile -> grid (ODIM/128, BROWS/256) = (8, 32) = 256 blocks = 1/CU
  gemm_kernel<<<dim3(ODIM / 128, BROWS / 256), 512, 0, stream>>>(A2, B2T, bias, out);
}